// Round 10
// baseline (8334.750 us; speedup 1.0000x reference)
//
#include <hip/hip_runtime.h>

typedef _Float16 half8 __attribute__((ext_vector_type(8)));
typedef float f32x4 __attribute__((ext_vector_type(4)));

#define MFMA(a,b,c) __builtin_amdgcn_mfma_f32_16x16x32_f16((a),(b),(c),0,0,0)

// ---- workspace map (bytes) ----
#define PKW_BYTES ((size_t)16*246*1024)                 // 4,030,464
#define OFF_ETAB  PKW_BYTES                             // Etab f32: 131,072
#define OFF_H0    (OFF_ETAB + (size_t)64*512*4)         // h0 f32: 2,097,152
#define OFF_XPRE  (OFF_H0 + (size_t)1024*512*4)
#define OFF_HPRE  (OFF_XPRE + (size_t)1024*128*512*2)
// end = 274,694,144 bytes (< proven ws floor 274,923,520)

__device__ __forceinline__ void gll16(const void* g, void* l){
  __builtin_amdgcn_global_load_lds(
      (const __attribute__((address_space(1))) void*)g,
      (__attribute__((address_space(3))) void*)l, 16, 0, 0);
}

// ======= packw: 16 per-wave streams, consumption order; 246 tiles/wave, 3KB chunks =======
// B  ts<192: c=ts/3 (chunk), a=ts%3 (gate r/z/n); i=c>>5, kq=(c>>1)&15, m=c&1 (0:W_ih 1:W_hh)
// D  ts in [192,225): td=ts-192<32: i=td>>4, ks=td&15 (W_o1 top); else pad
// E  ts in [225,243), w<4: te=ts-225<16 (W_o2); else pad.  ts in [243,246): pad
__global__ void packw_k(const float* __restrict__ W_ih, const float* __restrict__ W_hh,
                        const float* __restrict__ W_o1, const float* __restrict__ W_o2,
                        _Float16* __restrict__ pkw)
{
  int ts = blockIdx.x, w = blockIdx.y;
  int lane = threadIdx.x, lo = lane & 15, kb8 = (lane >> 4)*8;
  half8 v;
  #pragma unroll
  for (int e = 0; e < 8; e++) v[e] = (_Float16)0.f;
  if (ts < 192){
    int c = ts/3, a = ts%3;
    int i = (c >> 5) & 1, kq = (c >> 1) & 15, m = c & 1;
    int n = w*32 + i*16 + lo;
    const float* M = m ? W_hh : W_ih;
    #pragma unroll
    for (int e = 0; e < 8; e++){
      int k = kq*32 + kb8 + e;
      v[e] = (_Float16)M[(a*512 + n)*512 + k];
    }
  } else if (ts < 225){
    int td = ts - 192;
    if (td < 32){
      int i = td >> 4, ks = td & 15, n = w*32 + i*16 + lo;
      #pragma unroll
      for (int e = 0; e < 8; e++) v[e] = (_Float16)W_o1[(ks*32 + kb8 + e)*512 + n];
    }
  } else if (ts < 243 && w < 4){
    int te = ts - 225;
    if (te < 16){
      int n = w*16 + lo;
      #pragma unroll
      for (int e = 0; e < 8; e++) v[e] = (_Float16)W_o2[(te*32 + kb8 + e)*64 + n];
    }
  }
  *(half8*)(pkw + ((long)w*246 + ts)*512 + lane*8) = v;
}

// ---------------- Etab (f32) ----------------
__global__ void etab_k(const float* __restrict__ E, const float* __restrict__ W_in,
                       const float* __restrict__ b_in, float* __restrict__ Etab)
{
  int e = blockIdx.x, tid = threadIdx.x;
  __shared__ float er[256];
  if (tid < 256) er[tid] = E[e*256 + tid];
  __syncthreads();
  for (int j = tid; j < 512; j += 256){
    float acc = b_in[j];
    for (int k = 0; k < 256; k++) acc += er[k] * W_in[(256 + k)*512 + j];
    Etab[e*512 + j] = acc;
  }
}

// ---------------- h0 (f32) ----------------
__global__ __launch_bounds__(512) void h0_k(const float* __restrict__ ctx,
    const int* __restrict__ bh, const float* __restrict__ E,
    const float* __restrict__ W_init, const float* __restrict__ b_init,
    float* __restrict__ h0w)
{
  int b0 = blockIdx.x * 16, tid = threadIdx.x;
  __shared__ float cat[16][512];
  int c = tid & 255, rh = tid >> 8;
  for (int rr = 0; rr < 8; rr++){
    int r2 = rh*8 + rr;
    const float* p = ctx + ((b0 + r2)*128)*256 + c;
    float acc = 0.f;
    for (int t = 0; t < 128; t++) acc += p[t*256];
    cat[r2][c] = acc * (1.f/128.f);
    float s = 0.f;
    #pragma unroll
    for (int hh = 0; hh < 8; hh++){
      int e = bh[(b0 + r2)*8 + hh];
      s += E[e*256 + c];
    }
    cat[r2][256 + c] = s * 0.125f;
  }
  __syncthreads();
  int j = tid;
  float acc[16];
  #pragma unroll
  for (int r2 = 0; r2 < 16; r2++) acc[r2] = b_init[j];
  for (int k = 0; k < 512; k++){
    float wv = W_init[k*512 + j];
    #pragma unroll
    for (int r2 = 0; r2 < 16; r2++) acc[r2] += cat[r2][k] * wv;
  }
  #pragma unroll
  for (int r2 = 0; r2 < 16; r2++) h0w[(b0 + r2)*512 + j] = tanhf(acc[r2]);
}

// ---------------- prep: xpre = ctx@W_in_top, hpre = ctx@W_o1_bot (f16 out) ----------------
__global__ __launch_bounds__(512) void prep_k(const float* __restrict__ ctx,
    const float* __restrict__ W_in, const float* __restrict__ W_o1,
    _Float16* __restrict__ xpre, _Float16* __restrict__ hpre)
{
  int b = blockIdx.x, tid = threadIdx.x;
  int w = tid >> 6, lane = tid & 63, lo = lane & 15, hi = lane >> 4;
  extern __shared__ __align__(16) _Float16 A_lds[];   // 128 x 256 f16, swizzled

  {
    int ra = tid >> 2, ca = (tid & 3)*64;
    const float* p = ctx + ((long)b*128 + ra)*256 + ca;
    #pragma unroll
    for (int c8 = 0; c8 < 8; c8++){
      float4 f0 = *(const float4*)(p + c8*8);
      float4 f1 = *(const float4*)(p + c8*8 + 4);
      half8 v;
      v[0]=(_Float16)f0.x; v[1]=(_Float16)f0.y; v[2]=(_Float16)f0.z; v[3]=(_Float16)f0.w;
      v[4]=(_Float16)f1.x; v[5]=(_Float16)f1.y; v[6]=(_Float16)f1.z; v[7]=(_Float16)f1.w;
      *(half8*)((char*)A_lds + (((ra*512 + (ca + c8*8)*2)) ^ ((ra&7)<<4))) = v;
    }
  }
  __syncthreads();

  const float* Wb = (w < 4) ? W_in : (W_o1 + 512*512);
  _Float16* outp = (w < 4) ? xpre : hpre;
  const int colbase = (w & 3)*128;
  const int aswzp = (lo & 7) << 4;

  #pragma unroll 1
  for (int cth = 0; cth < 4; cth++){
    half8 bf0[8], bf1[8];
    const int n0 = colbase + cth*32 + lo;
    #pragma unroll
    for (int ks = 0; ks < 8; ks++){
      const int kb = ks*32 + hi*8;
      half8 v0, v1;
      #pragma unroll
      for (int e = 0; e < 8; e++){
        v0[e] = (_Float16)Wb[(kb + e)*512 + n0];
        v1[e] = (_Float16)Wb[(kb + e)*512 + n0 + 16];
      }
      bf0[ks] = v0; bf1[ks] = v1;
    }
    #pragma unroll 1
    for (int rt = 0; rt < 8; rt++){
      f32x4 acc0 = {0,0,0,0}, acc1 = {0,0,0,0};
      #pragma unroll
      for (int ks = 0; ks < 8; ks++){
        half8 a = *(const half8*)((const char*)A_lds +
                   ((((rt*16 + lo)*512 + hi*16 + ks*64)) ^ aswzp));
        acc0 = MFMA(a, bf0[ks], acc0);
        acc1 = MFMA(a, bf1[ks], acc1);
      }
      #pragma unroll
      for (int rr = 0; rr < 4; rr++){
        int t = rt*16 + hi*4 + rr;
        long rowoff = ((long)b*128 + t)*512 + colbase + cth*32;
        outp[rowoff +      lo] = (_Float16)acc0[rr];
        outp[rowoff + 16 + lo] = (_Float16)acc1[rr];
      }
    }
  }
}

// ====== main: 64 WGs x 1024 thr (16 waves x 32 cols); 3KB chunks, per-chunk drain ======
#define AFRAG(buf, base, ks) (*(const half8*)((const char*)(buf) + ((((base) + (ks)*64)) ^ aswz)))
#define WSTORE(buf, row, j, val) \
  *(_Float16*)((char*)(buf) + ((((row)*1024 + (j)*2)) ^ ((((row)&7))<<4))) = (_Float16)(val)
#define WSTORE8(buf, row, colf16, v8) \
  *(half8*)((char*)(buf) + ((((row)*1024 + (colf16)*2)) ^ ((((row)&7))<<4))) = (v8)

#define DRAIN do{ asm volatile("s_waitcnt vmcnt(0)" ::: "memory"); \
                  __builtin_amdgcn_sched_barrier(0); }while(0)

#define ISSUE(c_) do{ \
    const char* s_ = pkw_w + ((long)(c_))*3072 + (lane<<4); \
    char* d_ = ring + (((((c_)&1)<<4) + w)*3072); \
    gll16(s_,        d_); \
    gll16(s_ + 1024, d_ + 1024); \
    gll16(s_ + 2048, d_ + 2048); \
    __builtin_amdgcn_sched_barrier(0); \
  }while(0)

#define RFR(c_, f_) (*(const half8*)(ring + (((((c_)&1)<<4) + w)*3072) + ((f_)<<10) + (lane<<4)))

__global__ __launch_bounds__(1024) void main3_k(
    const _Float16* __restrict__ pkw, const float* __restrict__ Etab,
    const float* __restrict__ h0w, const _Float16* __restrict__ xpre,
    const _Float16* __restrict__ hpre, const int* __restrict__ bh,
    const float* __restrict__ b_ih, const float* __restrict__ b_hh,
    const float* __restrict__ lng, const float* __restrict__ lnb,
    const float* __restrict__ b_o1, const float* __restrict__ b_o2,
    float* __restrict__ out)
{
  const int g = blockIdx.x, tid = threadIdx.x;
  const int w = tid >> 6, lane = tid & 63, lo = lane & 15, hi = lane >> 4;
  const int r0 = g*16;

  extern __shared__ __align__(16) char smem[];
  char*      ring = smem;                          // 2 slots x 16 waves x 3072 = 98304
  _Float16*  h_s  = (_Float16*)(smem + 98304);     // 16x512 f16 swz
  _Float16*  hn_s = (_Float16*)(smem + 114688);
  _Float16*  xh_s = (_Float16*)(smem + 131072);    // x, then hidden
  float*     lg_s = (float*)(smem + 147456);       // 16x64
  float*     stats= (float*)(smem + 151552);       // [16][4][4][2]
  float*     murs = (float*)(smem + 153600);       // [16][2]
  int*       pb   = (int*)(smem + 153728);         // [16]

  float bcr[2], bcz[2], bin_[2], bhn[2], bo1v[2], lngv[2], lnbv[2];
  #pragma unroll
  for (int i = 0; i < 2; i++){
    int j = w*32 + i*16 + lo;
    bcr[i] = b_ih[j]     + b_hh[j];
    bcz[i] = b_ih[512+j] + b_hh[512+j];
    bin_[i]= b_ih[1024+j];
    bhn[i] = b_hh[1024+j];
    bo1v[i]= b_o1[j]; lngv[i]= lng[j]; lnbv[i]= lnb[j];
  }
  const float bo2v = (w < 4) ? b_o2[w*16 + lo] : 0.f;

  float hreg[2][4];
  #pragma unroll
  for (int i = 0; i < 2; i++)
    #pragma unroll
    for (int rr = 0; rr < 4; rr++)
      hreg[i][rr] = h0w[(r0 + hi*4 + rr)*512 + w*32 + i*16 + lo];

  {
    int rr = tid >> 6, c8 = tid & 63;
    const float* p = h0w + (r0 + rr)*512 + c8*8;
    half8 v;
    #pragma unroll
    for (int e = 0; e < 8; e++) v[e] = (_Float16)p[e];
    *(half8*)((char*)h_s + (((rr*1024 + c8*16)) ^ ((rr&7)<<4))) = v;
  }
  if (tid < 16) pb[tid] = bh[(r0 + tid)*8 + 7];

  const int aswz  = (lo & 7) << 4;
  const int abase = lo*1024 + hi*16;
  const char* pkw_w = (const char*)pkw + (long)w*246*1024;

  ISSUE(0);
  __syncthreads();   // implicit vmcnt(0): chunk 0 resident

  #pragma unroll 1
  for (int t = 0; t < 128; t++){
    // ---- A: x = relu(xpre + Etab[pb]) -> xh_s ----
    {
      int rowA = tid >> 6, c64 = (tid & 63)*8;
      const _Float16* xp = xpre + (((long)(r0 + rowA)*128 + t)*512) + c64;
      half8 x0 = *(const half8*)xp;
      const float* ep = Etab + pb[rowA]*512 + c64;
      float4 e0 = *(const float4*)(ep);
      float4 e1 = *(const float4*)(ep + 4);
      half8 o0;
      o0[0]=(_Float16)fmaxf((float)x0[0]+e0.x,0.f); o0[1]=(_Float16)fmaxf((float)x0[1]+e0.y,0.f);
      o0[2]=(_Float16)fmaxf((float)x0[2]+e0.z,0.f); o0[3]=(_Float16)fmaxf((float)x0[3]+e0.w,0.f);
      o0[4]=(_Float16)fmaxf((float)x0[4]+e1.x,0.f); o0[5]=(_Float16)fmaxf((float)x0[5]+e1.y,0.f);
      o0[6]=(_Float16)fmaxf((float)x0[6]+e1.z,0.f); o0[7]=(_Float16)fmaxf((float)x0[7]+e1.w,0.f);
      WSTORE8(xh_s, rowA, c64, o0);
    }
    __syncthreads();

    // ---- B: chunks 0..63 (3KB; {gi r,z,n}@kq then {gh r,z,n}@kq) ----
    float srow[4] = {0,0,0,0}, sqrow[4] = {0,0,0,0};
    #pragma unroll 1
    for (int i = 0; i < 2; i++){
      f32x4 a0={0,0,0,0},a1={0,0,0,0},a2={0,0,0,0},a3={0,0,0,0},a4={0,0,0,0},a5={0,0,0,0};
      #pragma unroll
      for (int kq = 0; kq < 16; kq++){
        const int c = (i*16 + kq)*2;
        ISSUE(c + 1);
        half8 ax = AFRAG(xh_s, abase, kq);
        a0 = MFMA(ax, RFR(c,0), a0);
        a1 = MFMA(ax, RFR(c,1), a1);
        a2 = MFMA(ax, RFR(c,2), a2);
        DRAIN;
        ISSUE(c + 2);
        half8 ah = AFRAG(h_s, abase, kq);
        a3 = MFMA(ah, RFR(c+1,0), a3);
        a4 = MFMA(ah, RFR(c+1,1), a4);
        a5 = MFMA(ah, RFR(c+1,2), a5);
        DRAIN;
      }
      #pragma unroll
      for (int rr = 0; rr < 4; rr++){
        float rg = 1.f/(1.f + __expf(-(a0[rr] + a3[rr] + bcr[i])));
        float zg = 1.f/(1.f + __expf(-(a1[rr] + a4[rr] + bcz[i])));
        float aa = (a2[rr] + bin_[i]) + rg*(a5[rr] + bhn[i]);
        float ea = __expf(-2.f*fabsf(aa));
        float th = (1.f - ea)/(1.f + ea);
        float ng = (aa < 0.f) ? -th : th;
        float hv = (1.f - zg)*ng + zg*hreg[i][rr];
        hreg[i][rr] = hv;
        srow[rr] += hv; sqrow[rr] += hv*hv;
      }
    }
    #pragma unroll
    for (int d = 1; d < 16; d <<= 1){
      #pragma unroll
      for (int rr = 0; rr < 4; rr++){
        srow[rr]  += __shfl_xor(srow[rr],  d);
        sqrow[rr] += __shfl_xor(sqrow[rr], d);
      }
    }
    if (lo == 0){
      #pragma unroll
      for (int rr = 0; rr < 4; rr++){
        stats[((w*4 + hi)*4 + rr)*2 + 0] = srow[rr];
        stats[((w*4 + hi)*4 + rr)*2 + 1] = sqrow[rr];
      }
    }
    __syncthreads();
    if (w == 0 && lane < 16){
      float s = 0.f, q = 0.f;
      #pragma unroll
      for (int ww = 0; ww < 16; ww++){
        s += stats[((ww*4 + (lane>>2))*4 + (lane&3))*2 + 0];
        q += stats[((ww*4 + (lane>>2))*4 + (lane&3))*2 + 1];
      }
      float mu = s*(1.f/512.f);
      float var = q*(1.f/512.f) - mu*mu;
      murs[lane*2 + 0] = mu;
      murs[lane*2 + 1] = rsqrtf(var + 1e-5f);
    }
    __syncthreads();

    // ---- C: h -> h_s, layernorm(h) -> hn_s; hpre gather ----
    float hp[2][4];
    #pragma unroll
    for (int rr = 0; rr < 4; rr++){
      int row = hi*4 + rr;
      float mu = murs[row*2 + 0], rs = murs[row*2 + 1];
      #pragma unroll
      for (int i = 0; i < 2; i++){
        int jc = w*32 + i*16 + lo;
        float hv = hreg[i][rr];
        WSTORE(h_s,  row, jc, hv);
        WSTORE(hn_s, row, jc, (hv - mu)*rs*lngv[i] + lnbv[i]);
        hp[i][rr] = (float)hpre[(((long)(r0 + row)*128 + t)*512) + jc];
      }
    }
    __syncthreads();

    // ---- D: chunks 64..74 (32 real tiles + 1 pad) ----
    {
      f32x4 d0={0,0,0,0}, d1={0,0,0,0};
      #pragma unroll
      for (int c6 = 0; c6 < 11; c6++){
        const int c = 64 + c6;
        ISSUE(c + 1);
        #pragma unroll
        for (int f = 0; f < 3; f++){
          const int td = c6*3 + f;
          if (td < 32){
            const int ks = td & 15;
            half8 a = AFRAG(hn_s, abase, ks);
            half8 bf = RFR(c, f);
            if (td < 16) d0 = MFMA(a, bf, d0);
            else         d1 = MFMA(a, bf, d1);
          }
        }
        DRAIN;
      }
      #pragma unroll
      for (int rr = 0; rr < 4; rr++){
        int row = hi*4 + rr;
        WSTORE(xh_s, row, w*32 +      lo, fmaxf(d0[rr] + bo1v[0] + hp[0][rr], 0.f));
        WSTORE(xh_s, row, w*32 + 16 + lo, fmaxf(d1[rr] + bo1v[1] + hp[1][rr], 0.f));
      }
    }
    __syncthreads();

    // ---- E: w<4: chunks 75..80 (16 real + 2 pad) + pad chunk 81; w>=4: pad chunk 75 ----
    if (w < 4){
      f32x4 eacc = {0,0,0,0};
      #pragma unroll
      for (int c6 = 0; c6 < 6; c6++){
        const int c = 75 + c6;
        ISSUE(c + 1);
        #pragma unroll
        for (int f = 0; f < 3; f++){
          const int te = c6*3 + f;
          if (te < 16)
            eacc = MFMA(AFRAG(xh_s, abase, te), RFR(c, f), eacc);
        }
        DRAIN;
      }
      ISSUE(0);   // iter c=81 (pad): prefetch next step's chunk 0
      DRAIN;
      #pragma unroll
      for (int rr = 0; rr < 4; rr++){
        int row = hi*4 + rr;
        lg_s[row*64 + w*16 + lo] = eacc[rr] + bo2v;
      }
    } else {
      ISSUE(0);   // iter c=75 (pad): prefetch next step's chunk 0
      DRAIN;
    }
    __syncthreads();

    // ---- F: out store + argmax (first-max tie), 1 row per wave ----
    {
      float v = lg_s[w*64 + lane];
      out[(((long)(r0 + w))*128 + t)*64 + lane] = v;
      int idx = lane;
      #pragma unroll
      for (int d = 1; d < 64; d <<= 1){
        float ov = __shfl_xor(v, d);
        int oi = __shfl_xor(idx, d);
        if (ov > v || (ov == v && oi < idx)){ v = ov; idx = oi; }
      }
      if (lane == 0) pb[w] = idx;
    }
    __syncthreads();
  }
}

extern "C" void kernel_launch(void* const* d_in, const int* in_sizes, int n_in,
                              void* d_out, int out_size, void* d_ws, size_t ws_size,
                              hipStream_t stream)
{
  const float* ctx    = (const float*)d_in[0];
  const int*   bh     = (const int*)d_in[1];
  const float* E      = (const float*)d_in[2];
  const float* W_in   = (const float*)d_in[3];
  const float* b_in   = (const float*)d_in[4];
  const float* W_init = (const float*)d_in[5];
  const float* b_init = (const float*)d_in[6];
  const float* W_ih   = (const float*)d_in[7];
  const float* W_hh   = (const float*)d_in[8];
  const float* b_ih   = (const float*)d_in[9];
  const float* b_hh   = (const float*)d_in[10];
  const float* ln_g   = (const float*)d_in[11];
  const float* ln_b   = (const float*)d_in[12];
  const float* W_o1   = (const float*)d_in[13];
  const float* b_o1   = (const float*)d_in[14];
  const float* W_o2   = (const float*)d_in[15];
  const float* b_o2   = (const float*)d_in[16];
  float* out = (float*)d_out;

  _Float16* pkw  = (_Float16*)d_ws;
  float*    Etab = (float*)((char*)d_ws + OFF_ETAB);
  float*    h0w  = (float*)((char*)d_ws + OFF_H0);
  _Float16* xpre = (_Float16*)((char*)d_ws + OFF_XPRE);
  _Float16* hpre = (_Float16*)((char*)d_ws + OFF_HPRE);

  (void)hipFuncSetAttribute((const void*)prep_k,
      hipFuncAttributeMaxDynamicSharedMemorySize, 65536);
  (void)hipFuncSetAttribute((const void*)main3_k,
      hipFuncAttributeMaxDynamicSharedMemorySize, 153792);

  hipLaunchKernelGGL(packw_k, dim3(246, 16), dim3(64), 0, stream, W_ih, W_hh, W_o1, W_o2, pkw);
  hipLaunchKernelGGL(etab_k, dim3(64), dim3(256), 0, stream, E, W_in, b_in, Etab);
  hipLaunchKernelGGL(h0_k, dim3(64), dim3(512), 0, stream, ctx, bh, E, W_init, b_init, h0w);
  hipLaunchKernelGGL(prep_k, dim3(1024), dim3(512), 65536, stream, ctx, W_in, W_o1, xpre, hpre);
  hipLaunchKernelGGL(main3_k, dim3(64), dim3(1024), 153792, stream,
                     pkw, Etab, h0w, xpre, hpre, bh,
                     b_ih, b_hh, ln_g, ln_b, b_o1, b_o2, out);
}

// Round 11
// 7475.381 us; speedup vs baseline: 1.1150x; 1.1150x over previous
//
#include <hip/hip_runtime.h>

typedef _Float16 half8 __attribute__((ext_vector_type(8)));
typedef float f32x4 __attribute__((ext_vector_type(4)));

#define MFMA(a,b,c) __builtin_amdgcn_mfma_f32_16x16x32_f16((a),(b),(c),0,0,0)

// ---- workspace map (bytes) ----
#define PKW_BYTES ((size_t)(4*468 + 4*456)*1024)        // 3,784,704
#define OFF_ETAB  PKW_BYTES                             // Etab f32: 131,072
#define OFF_H0    (OFF_ETAB + (size_t)64*512*4)         // h0 f32: 2,097,152
#define OFF_XPRE  (OFF_H0 + (size_t)1024*512*4)
#define OFF_HPRE  (OFF_XPRE + (size_t)1024*128*512*2)
// end = 274,448,384 bytes (< proven ws floor 274,923,520)

__device__ __forceinline__ void gll16(const void* g, void* l){
  __builtin_amdgcn_global_load_lds(
      (const __attribute__((address_space(1))) void*)g,
      (__attribute__((address_space(3))) void*)l, 16, 0, 0);
}

// ======= packw: per-wave stream, consumption order; 4KB chunks (4 tiles) =======
// ts<384: B: ts = i*96 + a*16 + kq  (a<3: W_ih gate a; a>=3: W_hh gate a-3)
// ts in [384,448): D: td=ts-384: i=td>>4, ks=td&15 (W_o1 top)
// w<4: ts in [448,464): E: te (W_o2); [464,468): pad   |  w>=4: [448,456): pad
__global__ void packw_k(const float* __restrict__ W_ih, const float* __restrict__ W_hh,
                        const float* __restrict__ W_o1, const float* __restrict__ W_o2,
                        _Float16* __restrict__ pkw)
{
  int ts = blockIdx.x, w = blockIdx.y;
  if (w >= 4 && ts >= 456) return;
  int lane = threadIdx.x, lo = lane & 15, kb8 = (lane >> 4)*8;
  half8 v;
  #pragma unroll
  for (int e = 0; e < 8; e++) v[e] = (_Float16)0.f;
  if (ts < 384){
    int i = ts/96, r = ts%96, a = r/16, kq = r%16;
    int n = w*64 + i*16 + lo;
    #pragma unroll
    for (int e = 0; e < 8; e++){
      int k = kq*32 + kb8 + e;
      v[e] = (a < 3) ? (_Float16)W_ih[(a*512 + n)*512 + k]
                     : (_Float16)W_hh[((a-3)*512 + n)*512 + k];
    }
  } else if (ts < 448){
    int td = ts - 384;
    int i = td >> 4, ks = td & 15, n = w*64 + i*16 + lo;
    #pragma unroll
    for (int e = 0; e < 8; e++) v[e] = (_Float16)W_o1[(ks*32 + kb8 + e)*512 + n];
  } else if (ts >= 448 && ts < 464 && w < 4){
    int te = ts - 448, n = w*16 + lo;
    #pragma unroll
    for (int e = 0; e < 8; e++) v[e] = (_Float16)W_o2[(te*32 + kb8 + e)*64 + n];
  }
  long base = (w < 4) ? (long)w*468 : (long)1872 + (long)(w-4)*456;
  *(half8*)(pkw + (base + ts)*512 + lane*8) = v;
}

// ---------------- Etab (f32) ----------------
__global__ void etab_k(const float* __restrict__ E, const float* __restrict__ W_in,
                       const float* __restrict__ b_in, float* __restrict__ Etab)
{
  int e = blockIdx.x, tid = threadIdx.x;
  __shared__ float er[256];
  if (tid < 256) er[tid] = E[e*256 + tid];
  __syncthreads();
  for (int j = tid; j < 512; j += 256){
    float acc = b_in[j];
    for (int k = 0; k < 256; k++) acc += er[k] * W_in[(256 + k)*512 + j];
    Etab[e*512 + j] = acc;
  }
}

// ---------------- h0 (f32) ----------------
__global__ __launch_bounds__(512) void h0_k(const float* __restrict__ ctx,
    const int* __restrict__ bh, const float* __restrict__ E,
    const float* __restrict__ W_init, const float* __restrict__ b_init,
    float* __restrict__ h0w)
{
  int b0 = blockIdx.x * 16, tid = threadIdx.x;
  __shared__ float cat[16][512];
  int c = tid & 255, rh = tid >> 8;
  for (int rr = 0; rr < 8; rr++){
    int r2 = rh*8 + rr;
    const float* p = ctx + ((b0 + r2)*128)*256 + c;
    float acc = 0.f;
    for (int t = 0; t < 128; t++) acc += p[t*256];
    cat[r2][c] = acc * (1.f/128.f);
    float s = 0.f;
    #pragma unroll
    for (int hh = 0; hh < 8; hh++){
      int e = bh[(b0 + r2)*8 + hh];
      s += E[e*256 + c];
    }
    cat[r2][256 + c] = s * 0.125f;
  }
  __syncthreads();
  int j = tid;
  float acc[16];
  #pragma unroll
  for (int r2 = 0; r2 < 16; r2++) acc[r2] = b_init[j];
  for (int k = 0; k < 512; k++){
    float wv = W_init[k*512 + j];
    #pragma unroll
    for (int r2 = 0; r2 < 16; r2++) acc[r2] += cat[r2][k] * wv;
  }
  #pragma unroll
  for (int r2 = 0; r2 < 16; r2++) h0w[(b0 + r2)*512 + j] = tanhf(acc[r2]);
}

// ---------------- prep: xpre = ctx@W_in_top, hpre = ctx@W_o1_bot (f16 out) ----------------
__global__ __launch_bounds__(512) void prep_k(const float* __restrict__ ctx,
    const float* __restrict__ W_in, const float* __restrict__ W_o1,
    _Float16* __restrict__ xpre, _Float16* __restrict__ hpre)
{
  int b = blockIdx.x, tid = threadIdx.x;
  int w = tid >> 6, lane = tid & 63, lo = lane & 15, hi = lane >> 4;
  extern __shared__ __align__(16) _Float16 A_lds[];

  {
    int ra = tid >> 2, ca = (tid & 3)*64;
    const float* p = ctx + ((long)b*128 + ra)*256 + ca;
    #pragma unroll
    for (int c8 = 0; c8 < 8; c8++){
      float4 f0 = *(const float4*)(p + c8*8);
      float4 f1 = *(const float4*)(p + c8*8 + 4);
      half8 v;
      v[0]=(_Float16)f0.x; v[1]=(_Float16)f0.y; v[2]=(_Float16)f0.z; v[3]=(_Float16)f0.w;
      v[4]=(_Float16)f1.x; v[5]=(_Float16)f1.y; v[6]=(_Float16)f1.z; v[7]=(_Float16)f1.w;
      *(half8*)((char*)A_lds + (((ra*512 + (ca + c8*8)*2)) ^ ((ra&7)<<4))) = v;
    }
  }
  __syncthreads();

  const float* Wb = (w < 4) ? W_in : (W_o1 + 512*512);
  _Float16* outp = (w < 4) ? xpre : hpre;
  const int colbase = (w & 3)*128;
  const int aswzp = (lo & 7) << 4;

  #pragma unroll 1
  for (int cth = 0; cth < 4; cth++){
    half8 bf0[8], bf1[8];
    const int n0 = colbase + cth*32 + lo;
    #pragma unroll
    for (int ks = 0; ks < 8; ks++){
      const int kb = ks*32 + hi*8;
      half8 v0, v1;
      #pragma unroll
      for (int e = 0; e < 8; e++){
        v0[e] = (_Float16)Wb[(kb + e)*512 + n0];
        v1[e] = (_Float16)Wb[(kb + e)*512 + n0 + 16];
      }
      bf0[ks] = v0; bf1[ks] = v1;
    }
    #pragma unroll 1
    for (int rt = 0; rt < 8; rt++){
      f32x4 acc0 = {0,0,0,0}, acc1 = {0,0,0,0};
      #pragma unroll
      for (int ks = 0; ks < 8; ks++){
        half8 a = *(const half8*)((const char*)A_lds +
                   ((((rt*16 + lo)*512 + hi*16 + ks*64)) ^ aswzp));
        acc0 = MFMA(a, bf0[ks], acc0);
        acc1 = MFMA(a, bf1[ks], acc1);
      }
      #pragma unroll
      for (int rr = 0; rr < 4; rr++){
        int t = rt*16 + hi*4 + rr;
        long rowoff = ((long)b*128 + t)*512 + colbase + cth*32;
        outp[rowoff +      lo] = (_Float16)acc0[rr];
        outp[rowoff + 16 + lo] = (_Float16)acc1[rr];
      }
    }
  }
}

// ====== main: 64 WGs x 512 thr; 4KB chunks, 3-slot ring, lookahead-2 vmcnt(8) ======
// Safety rule: counted waits appear ONLY in phases whose sole VMEM is the chunk
// stream (B, D, E). Phases with other VMEM (A: xpre/Etab, C: hpre, F: out) end
// with __syncthreads(), whose implicit vmcnt(0) fences all strays.
#define AFRAG(buf, base, ks) (*(const half8*)((const char*)(buf) + ((((base) + (ks)*64)) ^ aswz)))
#define WSTORE(buf, row, j, val) \
  *(_Float16*)((char*)(buf) + ((((row)*1024 + (j)*2)) ^ ((((row)&7))<<4))) = (_Float16)(val)
#define WSTORE8(buf, row, colf16, v8) \
  *(half8*)((char*)(buf) + ((((row)*1024 + (colf16)*2)) ^ ((((row)&7))<<4))) = (v8)

#define VMW8 do{ asm volatile("s_waitcnt vmcnt(8)" ::: "memory"); \
                 __builtin_amdgcn_sched_barrier(0); }while(0)

#define ISSUE4(c_, sl_) do{ \
    const char* s_ = pkw_w + (((long)(c_))<<12) + (lane<<4); \
    char* d_ = ring + ((((sl_)*8) + w)<<12); \
    gll16(s_,        d_); \
    gll16(s_ + 1024, d_ + 1024); \
    gll16(s_ + 2048, d_ + 2048); \
    gll16(s_ + 3072, d_ + 3072); \
    __builtin_amdgcn_sched_barrier(0); \
  }while(0)

#define RFR4(sl_, q_) (*(const half8*)(ring + ((((sl_)*8) + w)<<12) + ((q_)<<10) + (lane<<4)))

__global__ __launch_bounds__(512) void main4_k(
    const _Float16* __restrict__ pkw, const float* __restrict__ Etab,
    const float* __restrict__ h0w, const _Float16* __restrict__ xpre,
    const _Float16* __restrict__ hpre, const int* __restrict__ bh,
    const float* __restrict__ b_ih, const float* __restrict__ b_hh,
    const float* __restrict__ lng, const float* __restrict__ lnb,
    const float* __restrict__ b_o1, const float* __restrict__ b_o2,
    float* __restrict__ out)
{
  const int g = blockIdx.x, tid = threadIdx.x;
  const int w = tid >> 6, lane = tid & 63, lo = lane & 15, hi = lane >> 4;
  const int r0 = g*16;

  extern __shared__ __align__(16) char smem[];
  char*      ring = smem;                          // 3 slots x 8 waves x 4096 = 98304
  _Float16*  h_s  = (_Float16*)(smem + 98304);
  _Float16*  hn_s = (_Float16*)(smem + 114688);
  _Float16*  xh_s = (_Float16*)(smem + 131072);
  float*     lg_s = (float*)(smem + 147456);
  float*     stats= (float*)(smem + 151552);
  float*     murs = (float*)(smem + 152576);
  int*       pb   = (int*)(smem + 152704);

  float bcr[4], bcz[4], bin_[4], bhn[4], bo1v[4], lngv[4], lnbv[4];
  #pragma unroll
  for (int i = 0; i < 4; i++){
    int j = w*64 + i*16 + lo;
    bcr[i] = b_ih[j]     + b_hh[j];
    bcz[i] = b_ih[512+j] + b_hh[512+j];
    bin_[i]= b_ih[1024+j];
    bhn[i] = b_hh[1024+j];
    bo1v[i]= b_o1[j]; lngv[i]= lng[j]; lnbv[i]= lnb[j];
  }
  const float bo2v = (w < 4) ? b_o2[w*16 + lo] : 0.f;

  float hreg[4][4];
  #pragma unroll
  for (int i = 0; i < 4; i++)
    #pragma unroll
    for (int rr = 0; rr < 4; rr++)
      hreg[i][rr] = h0w[(r0 + hi*4 + rr)*512 + w*64 + i*16 + lo];

  #pragma unroll
  for (int c2 = 0; c2 < 2; c2++){
    int ch = tid*2 + c2, rr = ch >> 6, c8 = ch & 63;
    const float* p = h0w + (r0 + rr)*512 + c8*8;
    half8 v;
    #pragma unroll
    for (int e = 0; e < 8; e++) v[e] = (_Float16)p[e];
    *(half8*)((char*)h_s + (((rr*1024 + c8*16)) ^ ((rr&7)<<4))) = v;
  }
  if (tid < 16) pb[tid] = bh[(r0 + tid)*8 + 7];

  const int aswz  = (lo & 7) << 4;
  const int abase = lo*1024 + hi*16;
  const char* pkw_w = (const char*)pkw +
      ((w < 4) ? (long)w*468*1024 : ((long)1872 + (long)(w-4)*456)*1024);

  ISSUE4(0, 0);
  ISSUE4(1, 1);
  __syncthreads();   // full drain: chunks 0,1 resident

  #pragma unroll 1
  for (int t = 0; t < 128; t++){
    // ---- A: x = relu(xpre + Etab[pb]) -> xh_s (nontemporal xpre) ----
    {
      int rowA = tid >> 5, c32 = (tid & 31)*16;
      const _Float16* xp = xpre + (((long)(r0 + rowA)*128 + t)*512) + c32;
      half8 x0 = __builtin_nontemporal_load((const half8*)xp);
      half8 x1 = __builtin_nontemporal_load((const half8*)(xp + 8));
      const float* ep = Etab + pb[rowA]*512 + c32;
      float4 e0 = *(const float4*)(ep);
      float4 e1 = *(const float4*)(ep + 4);
      float4 e2 = *(const float4*)(ep + 8);
      float4 e3 = *(const float4*)(ep + 12);
      half8 o0, o1;
      o0[0]=(_Float16)fmaxf((float)x0[0]+e0.x,0.f); o0[1]=(_Float16)fmaxf((float)x0[1]+e0.y,0.f);
      o0[2]=(_Float16)fmaxf((float)x0[2]+e0.z,0.f); o0[3]=(_Float16)fmaxf((float)x0[3]+e0.w,0.f);
      o0[4]=(_Float16)fmaxf((float)x0[4]+e1.x,0.f); o0[5]=(_Float16)fmaxf((float)x0[5]+e1.y,0.f);
      o0[6]=(_Float16)fmaxf((float)x0[6]+e1.z,0.f); o0[7]=(_Float16)fmaxf((float)x0[7]+e1.w,0.f);
      o1[0]=(_Float16)fmaxf((float)x1[0]+e2.x,0.f); o1[1]=(_Float16)fmaxf((float)x1[1]+e2.y,0.f);
      o1[2]=(_Float16)fmaxf((float)x1[2]+e2.z,0.f); o1[3]=(_Float16)fmaxf((float)x1[3]+e2.w,0.f);
      o1[4]=(_Float16)fmaxf((float)x1[4]+e3.x,0.f); o1[5]=(_Float16)fmaxf((float)x1[5]+e3.y,0.f);
      o1[6]=(_Float16)fmaxf((float)x1[6]+e3.z,0.f); o1[7]=(_Float16)fmaxf((float)x1[7]+e3.w,0.f);
      WSTORE8(xh_s, rowA, c32,     o0);
      WSTORE8(xh_s, rowA, c32 + 8, o1);
    }
    __syncthreads();   // drains stray xpre/Etab loads -> B's counted waits are clean

    // ---- B: chunks 0..95; 6 single-acc passes per i; lookahead-2 vmcnt(8) ----
    float srow[4] = {0,0,0,0}, sqrow[4] = {0,0,0,0};
    #pragma unroll 1
    for (int i = 0; i < 4; i++){
      f32x4 a0={0,0,0,0},a1={0,0,0,0},a2={0,0,0,0},a3={0,0,0,0},a4={0,0,0,0},a5={0,0,0,0};
      #pragma unroll
      for (int a6 = 0; a6 < 6; a6++){
        #pragma unroll
        for (int cq = 0; cq < 4; cq++){
          const int pidx = i*24 + a6*4 + cq;      // chunk being consumed
          ISSUE4(pidx + 2, (a6*4 + cq + 2) % 3);  // i*24 % 3 == 0 -> slot static
          VMW8;                                    // guarantees chunk pidx landed
          #pragma unroll
          for (int q = 0; q < 4; q++){
            half8 af = AFRAG((a6 < 3) ? xh_s : h_s, abase, cq*4 + q);
            half8 bf = RFR4((a6*4 + cq) % 3, q);
            if      (a6 == 0) a0 = MFMA(af, bf, a0);
            else if (a6 == 1) a1 = MFMA(af, bf, a1);
            else if (a6 == 2) a2 = MFMA(af, bf, a2);
            else if (a6 == 3) a3 = MFMA(af, bf, a3);
            else if (a6 == 4) a4 = MFMA(af, bf, a4);
            else              a5 = MFMA(af, bf, a5);
          }
        }
      }
      #pragma unroll
      for (int rr = 0; rr < 4; rr++){
        float rg = 1.f/(1.f + __expf(-(a0[rr] + a3[rr] + bcr[i])));
        float zg = 1.f/(1.f + __expf(-(a1[rr] + a4[rr] + bcz[i])));
        float aa = (a2[rr] + bin_[i]) + rg*(a5[rr] + bhn[i]);
        float ea = __expf(-2.f*fabsf(aa));
        float th = (1.f - ea)/(1.f + ea);
        float ng = (aa < 0.f) ? -th : th;
        float hv = (1.f - zg)*ng + zg*hreg[i][rr];
        hreg[i][rr] = hv;
        srow[rr] += hv; sqrow[rr] += hv*hv;
      }
    }
    #pragma unroll
    for (int d = 1; d < 16; d <<= 1){
      #pragma unroll
      for (int rr = 0; rr < 4; rr++){
        srow[rr]  += __shfl_xor(srow[rr],  d);
        sqrow[rr] += __shfl_xor(sqrow[rr], d);
      }
    }
    if (lo == 0){
      #pragma unroll
      for (int rr = 0; rr < 4; rr++){
        stats[((w*4 + hi)*4 + rr)*2 + 0] = srow[rr];
        stats[((w*4 + hi)*4 + rr)*2 + 1] = sqrow[rr];
      }
    }
    __syncthreads();
    if (w == 0 && lane < 16){
      float s = 0.f, q = 0.f;
      #pragma unroll
      for (int ww = 0; ww < 8; ww++){
        s += stats[((ww*4 + (lane>>2))*4 + (lane&3))*2 + 0];
        q += stats[((ww*4 + (lane>>2))*4 + (lane&3))*2 + 1];
      }
      float mu = s*(1.f/512.f);
      float var = q*(1.f/512.f) - mu*mu;
      murs[lane*2 + 0] = mu;
      murs[lane*2 + 1] = rsqrtf(var + 1e-5f);
    }
    __syncthreads();

    // ---- C: h -> h_s, layernorm(h) -> hn_s; hpre gather (nontemporal) ----
    float hp[4][4];
    #pragma unroll
    for (int rr = 0; rr < 4; rr++){
      int row = hi*4 + rr;
      float mu = murs[row*2 + 0], rs = murs[row*2 + 1];
      #pragma unroll
      for (int i = 0; i < 4; i++){
        int jc = w*64 + i*16 + lo;
        float hv = hreg[i][rr];
        WSTORE(h_s,  row, jc, hv);
        WSTORE(hn_s, row, jc, (hv - mu)*rs*lngv[i] + lnbv[i]);
        hp[i][rr] = (float)__builtin_nontemporal_load(
            &hpre[(((long)(r0 + row)*128 + t)*512) + jc]);
      }
    }
    __syncthreads();   // drains stray hpre loads -> D's counted waits are clean

    // ---- D: chunks 96..111 (4 per i), per-i acc, immediate WSTORE ----
    #pragma unroll
    for (int i = 0; i < 4; i++){
      f32x4 dacc = {0,0,0,0};
      #pragma unroll
      for (int cq = 0; cq < 4; cq++){
        const int pidx = 96 + i*4 + cq;
        ISSUE4(pidx + 2, (i*4 + cq + 2) % 3);     // 96 % 3 == 0
        VMW8;
        #pragma unroll
        for (int q = 0; q < 4; q++)
          dacc = MFMA(AFRAG(hn_s, abase, cq*4 + q), RFR4((i*4 + cq) % 3, q), dacc);
      }
      #pragma unroll
      for (int rr = 0; rr < 4; rr++){
        int row = hi*4 + rr;
        WSTORE(xh_s, row, w*64 + i*16 + lo, fmaxf(dacc[rr] + bo1v[i] + hp[i][rr], 0.f));
      }
    }
    __syncthreads();

    // ---- E: w<4: chunks 112..115 + pad 116; w>=4: pads 112,113 ----
    if (w < 4){
      f32x4 eacc = {0,0,0,0};
      #pragma unroll
      for (int cq = 0; cq < 4; cq++){
        const int pidx = 112 + cq;                       // slots: 1,2,0,1
        const int nx  = (cq < 3) ? (114 + cq) : 0;       // wrap 117 -> 0
        ISSUE4(nx, nx % 3);
        VMW8;
        #pragma unroll
        for (int q = 0; q < 4; q++)
          eacc = MFMA(AFRAG(xh_s, abase, cq*4 + q), RFR4(pidx % 3, q), eacc);
      }
      ISSUE4(1, 1);   // event p=116 (pad): prefetch next step's chunk 1
      VMW8;
      #pragma unroll
      for (int rr = 0; rr < 4; rr++){
        int row = hi*4 + rr;
        lg_s[row*64 + w*16 + lo] = eacc[rr] + bo2v;
      }
    } else {
      ISSUE4(0, 0);   // event p=112 (pad)
      VMW8;
      ISSUE4(1, 1);   // event p=113 (pad)
      VMW8;
    }
    __syncthreads();   // full drain: next step's chunks 0,1 resident; out-stores fenced below

    // ---- F: out store (nontemporal) + argmax (first-max tie), 2 rows/wave ----
    #pragma unroll
    for (int sub = 0; sub < 2; sub++){
      int r2 = w*2 + sub;
      float v = lg_s[r2*64 + lane];
      __builtin_nontemporal_store(v, &out[(((long)(r0 + r2))*128 + t)*64 + lane]);
      int idx = lane;
      #pragma unroll
      for (int d = 1; d < 64; d <<= 1){
        float ov = __shfl_xor(v, d);
        int oi = __shfl_xor(idx, d);
        if (ov > v || (ov == v && oi < idx)){ v = ov; idx = oi; }
      }
      if (lane == 0) pb[r2] = idx;
    }
    __syncthreads();   // drains out-stores -> next A/B clean
  }
}

extern "C" void kernel_launch(void* const* d_in, const int* in_sizes, int n_in,
                              void* d_out, int out_size, void* d_ws, size_t ws_size,
                              hipStream_t stream)
{
  const float* ctx    = (const float*)d_in[0];
  const int*   bh     = (const int*)d_in[1];
  const float* E      = (const float*)d_in[2];
  const float* W_in   = (const float*)d_in[3];
  const float* b_in   = (const float*)d_in[4];
  const float* W_init = (const float*)d_in[5];
  const float* b_init = (const float*)d_in[6];
  const float* W_ih   = (const float*)d_in[7];
  const float* W_hh   = (const float*)d_in[8];
  const float* b_ih   = (const float*)d_in[9];
  const float* b_hh   = (const float*)d_in[10];
  const float* ln_g   = (const float*)d_in[11];
  const float* ln_b   = (const float*)d_in[12];
  const float* W_o1   = (const float*)d_in[13];
  const float* b_o1   = (const float*)d_in[14];
  const float* W_o2   = (const float*)d_in[15];
  const float* b_o2   = (const float*)d_in[16];
  float* out = (float*)d_out;

  _Float16* pkw  = (_Float16*)d_ws;
  float*    Etab = (float*)((char*)d_ws + OFF_ETAB);
  float*    h0w  = (float*)((char*)d_ws + OFF_H0);
  _Float16* xpre = (_Float16*)((char*)d_ws + OFF_XPRE);
  _Float16* hpre = (_Float16*)((char*)d_ws + OFF_HPRE);

  (void)hipFuncSetAttribute((const void*)prep_k,
      hipFuncAttributeMaxDynamicSharedMemorySize, 65536);
  (void)hipFuncSetAttribute((const void*)main4_k,
      hipFuncAttributeMaxDynamicSharedMemorySize, 152768);

  hipLaunchKernelGGL(packw_k, dim3(468, 8), dim3(64), 0, stream, W_ih, W_hh, W_o1, W_o2, pkw);
  hipLaunchKernelGGL(etab_k, dim3(64), dim3(256), 0, stream, E, W_in, b_in, Etab);
  hipLaunchKernelGGL(h0_k, dim3(64), dim3(512), 0, stream, ctx, bh, E, W_init, b_init, h0w);
  hipLaunchKernelGGL(prep_k, dim3(1024), dim3(512), 65536, stream, ctx, W_in, W_o1, xpre, hpre);
  hipLaunchKernelGGL(main4_k, dim3(64), dim3(512), 152768, stream,
                     pkw, Etab, h0w, xpre, hpre, bh,
                     b_ih, b_hh, ln_g, ln_b, b_o1, b_o2, out);
}

// Round 15
// 5570.316 us; speedup vs baseline: 1.4963x; 1.3420x over previous
//
#include <hip/hip_runtime.h>

typedef _Float16 half8 __attribute__((ext_vector_type(8)));
typedef float f32x4 __attribute__((ext_vector_type(4)));

#define MFMA(a,b,c) __builtin_amdgcn_mfma_f32_16x16x32_f16((a),(b),(c),0,0,0)

// ---- workspace map (bytes) ----
#define PKW_BYTES ((size_t)(4*468 + 4*456)*1024)        // 3,784,704
#define OFF_ETAB  PKW_BYTES                             // Etab f32: 131,072
#define OFF_H0    (OFF_ETAB + (size_t)64*512*4)         // h0 f32: 2,097,152
#define OFF_XPRE  (OFF_H0 + (size_t)1024*512*4)
#define OFF_HPRE  (OFF_XPRE + (size_t)1024*128*512*2)
// end = 274,448,384 bytes (< proven ws floor 274,923,520)

__device__ __forceinline__ void gll16(const void* g, void* l){
  __builtin_amdgcn_global_load_lds(
      (const __attribute__((address_space(1))) void*)g,
      (__attribute__((address_space(3))) void*)l, 16, 0, 0);
}

// ======= packw (r11-proven, unchanged): per-wave stream, consumption order =======
// ts<384: B: ts = i*96 + a*16 + kq  (a<3: W_ih gate a; a>=3: W_hh gate a-3)
// ts in [384,448): D: td=ts-384: i=td>>4, ks=td&15 (W_o1 top)   [reg path now]
// w<4: ts in [448,464): E (W_o2) [reg path]; [464,468): pad | w>=4: [448,456): pad
__global__ void packw_k(const float* __restrict__ W_ih, const float* __restrict__ W_hh,
                        const float* __restrict__ W_o1, const float* __restrict__ W_o2,
                        _Float16* __restrict__ pkw)
{
  int ts = blockIdx.x, w = blockIdx.y;
  if (w >= 4 && ts >= 456) return;
  int lane = threadIdx.x, lo = lane & 15, kb8 = (lane >> 4)*8;
  half8 v;
  #pragma unroll
  for (int e = 0; e < 8; e++) v[e] = (_Float16)0.f;
  if (ts < 384){
    int i = ts/96, r = ts%96, a = r/16, kq = r%16;
    int n = w*64 + i*16 + lo;
    #pragma unroll
    for (int e = 0; e < 8; e++){
      int k = kq*32 + kb8 + e;
      v[e] = (a < 3) ? (_Float16)W_ih[(a*512 + n)*512 + k]
                     : (_Float16)W_hh[((a-3)*512 + n)*512 + k];
    }
  } else if (ts < 448){
    int td = ts - 384;
    int i = td >> 4, ks = td & 15, n = w*64 + i*16 + lo;
    #pragma unroll
    for (int e = 0; e < 8; e++) v[e] = (_Float16)W_o1[(ks*32 + kb8 + e)*512 + n];
  } else if (ts >= 448 && ts < 464 && w < 4){
    int te = ts - 448, n = w*16 + lo;
    #pragma unroll
    for (int e = 0; e < 8; e++) v[e] = (_Float16)W_o2[(te*32 + kb8 + e)*64 + n];
  }
  long base = (w < 4) ? (long)w*468 : (long)1872 + (long)(w-4)*456;
  *(half8*)(pkw + (base + ts)*512 + lane*8) = v;
}

// ---------------- Etab (f32) ----------------
__global__ void etab_k(const float* __restrict__ E, const float* __restrict__ W_in,
                       const float* __restrict__ b_in, float* __restrict__ Etab)
{
  int e = blockIdx.x, tid = threadIdx.x;
  __shared__ float er[256];
  if (tid < 256) er[tid] = E[e*256 + tid];
  __syncthreads();
  for (int j = tid; j < 512; j += 256){
    float acc = b_in[j];
    for (int k = 0; k < 256; k++) acc += er[k] * W_in[(256 + k)*512 + j];
    Etab[e*512 + j] = acc;
  }
}

// ---------------- h0 (f32) ----------------
__global__ __launch_bounds__(512) void h0_k(const float* __restrict__ ctx,
    const int* __restrict__ bh, const float* __restrict__ E,
    const float* __restrict__ W_init, const float* __restrict__ b_init,
    float* __restrict__ h0w)
{
  int b0 = blockIdx.x * 16, tid = threadIdx.x;
  __shared__ float cat[16][512];
  int c = tid & 255, rh = tid >> 8;
  for (int rr = 0; rr < 8; rr++){
    int r2 = rh*8 + rr;
    const float* p = ctx + ((b0 + r2)*128)*256 + c;
    float acc = 0.f;
    for (int t = 0; t < 128; t++) acc += p[t*256];
    cat[r2][c] = acc * (1.f/128.f);
    float s = 0.f;
    #pragma unroll
    for (int hh = 0; hh < 8; hh++){
      int e = bh[(b0 + r2)*8 + hh];
      s += E[e*256 + c];
    }
    cat[r2][256 + c] = s * 0.125f;
  }
  __syncthreads();
  int j = tid;
  float acc[16];
  #pragma unroll
  for (int r2 = 0; r2 < 16; r2++) acc[r2] = b_init[j];
  for (int k = 0; k < 512; k++){
    float wv = W_init[k*512 + j];
    #pragma unroll
    for (int r2 = 0; r2 < 16; r2++) acc[r2] += cat[r2][k] * wv;
  }
  #pragma unroll
  for (int r2 = 0; r2 < 16; r2++) h0w[(b0 + r2)*512 + j] = tanhf(acc[r2]);
}

// ---------------- prep: xpre = ctx@W_in_top, hpre = ctx@W_o1_bot (f16 out) ----------------
__global__ __launch_bounds__(512) void prep_k(const float* __restrict__ ctx,
    const float* __restrict__ W_in, const float* __restrict__ W_o1,
    _Float16* __restrict__ xpre, _Float16* __restrict__ hpre)
{
  int b = blockIdx.x, tid = threadIdx.x;
  int w = tid >> 6, lane = tid & 63, lo = lane & 15, hi = lane >> 4;
  extern __shared__ __align__(16) _Float16 A_lds[];

  {
    int ra = tid >> 2, ca = (tid & 3)*64;
    const float* p = ctx + ((long)b*128 + ra)*256 + ca;
    #pragma unroll
    for (int c8 = 0; c8 < 8; c8++){
      float4 f0 = *(const float4*)(p + c8*8);
      float4 f1 = *(const float4*)(p + c8*8 + 4);
      half8 v;
      v[0]=(_Float16)f0.x; v[1]=(_Float16)f0.y; v[2]=(_Float16)f0.z; v[3]=(_Float16)f0.w;
      v[4]=(_Float16)f1.x; v[5]=(_Float16)f1.y; v[6]=(_Float16)f1.z; v[7]=(_Float16)f1.w;
      *(half8*)((char*)A_lds + (((ra*512 + (ca + c8*8)*2)) ^ ((ra&7)<<4))) = v;
    }
  }
  __syncthreads();

  const float* Wb = (w < 4) ? W_in : (W_o1 + 512*512);
  _Float16* outp = (w < 4) ? xpre : hpre;
  const int colbase = (w & 3)*128;
  const int aswzp = (lo & 7) << 4;

  #pragma unroll 1
  for (int cth = 0; cth < 4; cth++){
    half8 bf0[8], bf1[8];
    const int n0 = colbase + cth*32 + lo;
    #pragma unroll
    for (int ks = 0; ks < 8; ks++){
      const int kb = ks*32 + hi*8;
      half8 v0, v1;
      #pragma unroll
      for (int e = 0; e < 8; e++){
        v0[e] = (_Float16)Wb[(kb + e)*512 + n0];
        v1[e] = (_Float16)Wb[(kb + e)*512 + n0 + 16];
      }
      bf0[ks] = v0; bf1[ks] = v1;
    }
    #pragma unroll 1
    for (int rt = 0; rt < 8; rt++){
      f32x4 acc0 = {0,0,0,0}, acc1 = {0,0,0,0};
      #pragma unroll
      for (int ks = 0; ks < 8; ks++){
        half8 a = *(const half8*)((const char*)A_lds +
                   ((((rt*16 + lo)*512 + hi*16 + ks*64)) ^ aswzp));
        acc0 = MFMA(a, bf0[ks], acc0);
        acc1 = MFMA(a, bf1[ks], acc1);
      }
      #pragma unroll
      for (int rr = 0; rr < 4; rr++){
        int t = rt*16 + hi*4 + rr;
        long rowoff = ((long)b*128 + t)*512 + colbase + cth*32;
        outp[rowoff +      lo] = (_Float16)acc0[rr];
        outp[rowoff + 16 + lo] = (_Float16)acc1[rr];
      }
    }
  }
}

// ====== main: 64 WGs x 512 thr; B = r11-proven ring (4KB/3-slot/VMW8); D,E = reg path ======
// Counted waits ONLY in B (sole VMEM = chunk stream). A/C/D/E/F end with
// __syncthreads() (full vmcnt drain); D/E use compiler-managed register loads.
#define AFRAG(buf, base, ks) (*(const half8*)((const char*)(buf) + ((((base) + (ks)*64)) ^ aswz)))
#define WSTORE(buf, row, j, val) \
  *(_Float16*)((char*)(buf) + ((((row)*1024 + (j)*2)) ^ ((((row)&7))<<4))) = (_Float16)(val)
#define WSTORE8(buf, row, colf16, v8) \
  *(half8*)((char*)(buf) + ((((row)*1024 + (colf16)*2)) ^ ((((row)&7))<<4))) = (v8)

#define VMW8 do{ asm volatile("s_waitcnt vmcnt(8)" ::: "memory"); \
                 __builtin_amdgcn_sched_barrier(0); }while(0)

#define ISSUE4(c_, sl_) do{ \
    int cw_ = (c_); if (cw_ >= 96) cw_ -= 96; \
    const char* s_ = pkw_w + (((long)cw_)<<12) + (lane<<4); \
    char* d_ = ring + ((((sl_)*8) + w)<<12); \
    gll16(s_,        d_); \
    gll16(s_ + 1024, d_ + 1024); \
    gll16(s_ + 2048, d_ + 2048); \
    gll16(s_ + 3072, d_ + 3072); \
    __builtin_amdgcn_sched_barrier(0); \
  }while(0)

#define RFR4(sl_, q_) (*(const half8*)(ring + ((((sl_)*8) + w)<<12) + ((q_)<<10) + (lane<<4)))

__global__ __launch_bounds__(512) void main8_k(
    const _Float16* __restrict__ pkw, const float* __restrict__ Etab,
    const float* __restrict__ h0w, const _Float16* __restrict__ xpre,
    const _Float16* __restrict__ hpre, const int* __restrict__ bh,
    const float* __restrict__ b_ih, const float* __restrict__ b_hh,
    const float* __restrict__ lng, const float* __restrict__ lnb,
    const float* __restrict__ b_o1, const float* __restrict__ b_o2,
    float* __restrict__ out)
{
  const int g = blockIdx.x, tid = threadIdx.x;
  const int w = tid >> 6, lane = tid & 63, lo = lane & 15, hi = lane >> 4;
  const int r0 = g*16;

  extern __shared__ __align__(16) char smem[];
  char*      ring = smem;                          // 3 slots x 8 waves x 4096 = 98304
  _Float16*  h_s  = (_Float16*)(smem + 98304);
  _Float16*  hn_s = (_Float16*)(smem + 114688);
  _Float16*  xh_s = (_Float16*)(smem + 131072);
  float*     lg_s = (float*)(smem + 147456);
  float*     stats= (float*)(smem + 151552);
  float*     murs = (float*)(smem + 152576);
  int*       pb   = (int*)(smem + 152704);

  float bcr[4], bcz[4], bin_[4], bhn[4], bo1v[4], lngv[4], lnbv[4];
  #pragma unroll
  for (int i = 0; i < 4; i++){
    int j = w*64 + i*16 + lo;
    bcr[i] = b_ih[j]     + b_hh[j];
    bcz[i] = b_ih[512+j] + b_hh[512+j];
    bin_[i]= b_ih[1024+j];
    bhn[i] = b_hh[1024+j];
    bo1v[i]= b_o1[j]; lngv[i]= lng[j]; lnbv[i]= lnb[j];
  }
  const float bo2v = (w < 4) ? b_o2[w*16 + lo] : 0.f;

  float hreg[4][4];
  #pragma unroll
  for (int i = 0; i < 4; i++)
    #pragma unroll
    for (int rr = 0; rr < 4; rr++)
      hreg[i][rr] = h0w[(r0 + hi*4 + rr)*512 + w*64 + i*16 + lo];

  #pragma unroll
  for (int c2 = 0; c2 < 2; c2++){
    int ch = tid*2 + c2, rr = ch >> 6, c8 = ch & 63;
    const float* p = h0w + (r0 + rr)*512 + c8*8;
    half8 v;
    #pragma unroll
    for (int e = 0; e < 8; e++) v[e] = (_Float16)p[e];
    *(half8*)((char*)h_s + (((rr*1024 + c8*16)) ^ ((rr&7)<<4))) = v;
  }
  if (tid < 16) pb[tid] = bh[(r0 + tid)*8 + 7];

  const int aswz  = (lo & 7) << 4;
  const int abase = lo*1024 + hi*16;
  const char* pkw_w = (const char*)pkw +
      ((w < 4) ? (long)w*468*1024 : ((long)1872 + (long)(w-4)*456)*1024);

  ISSUE4(0, 0);
  ISSUE4(1, 1);
  __syncthreads();   // full drain: chunks 0,1 resident

  #pragma unroll 1
  for (int t = 0; t < 128; t++){
    // ---- A: x = relu(xpre + Etab[pb]) -> xh_s (nt xpre); ends with full drain ----
    {
      int rowA = tid >> 5, c32 = (tid & 31)*16;
      const _Float16* xp = xpre + (((long)(r0 + rowA)*128 + t)*512) + c32;
      half8 x0 = __builtin_nontemporal_load((const half8*)xp);
      half8 x1 = __builtin_nontemporal_load((const half8*)(xp + 8));
      const float* ep = Etab + pb[rowA]*512 + c32;
      float4 e0 = *(const float4*)(ep);
      float4 e1 = *(const float4*)(ep + 4);
      float4 e2 = *(const float4*)(ep + 8);
      float4 e3 = *(const float4*)(ep + 12);
      half8 o0, o1;
      o0[0]=(_Float16)fmaxf((float)x0[0]+e0.x,0.f); o0[1]=(_Float16)fmaxf((float)x0[1]+e0.y,0.f);
      o0[2]=(_Float16)fmaxf((float)x0[2]+e0.z,0.f); o0[3]=(_Float16)fmaxf((float)x0[3]+e0.w,0.f);
      o0[4]=(_Float16)fmaxf((float)x0[4]+e1.x,0.f); o0[5]=(_Float16)fmaxf((float)x0[5]+e1.y,0.f);
      o0[6]=(_Float16)fmaxf((float)x0[6]+e1.z,0.f); o0[7]=(_Float16)fmaxf((float)x0[7]+e1.w,0.f);
      o1[0]=(_Float16)fmaxf((float)x1[0]+e2.x,0.f); o1[1]=(_Float16)fmaxf((float)x1[1]+e2.y,0.f);
      o1[2]=(_Float16)fmaxf((float)x1[2]+e2.z,0.f); o1[3]=(_Float16)fmaxf((float)x1[3]+e2.w,0.f);
      o1[4]=(_Float16)fmaxf((float)x1[4]+e3.x,0.f); o1[5]=(_Float16)fmaxf((float)x1[5]+e3.y,0.f);
      o1[6]=(_Float16)fmaxf((float)x1[6]+e3.z,0.f); o1[7]=(_Float16)fmaxf((float)x1[7]+e3.w,0.f);
      WSTORE8(xh_s, rowA, c32,     o0);
      WSTORE8(xh_s, rowA, c32 + 8, o1);
    }
    __syncthreads();   // drains stray xpre/Etab loads -> B's counted waits are clean

    // ---- B: chunks 0..95 (r11-proven ring); tail issues wrap to next step's 0,1 ----
    float srow[4] = {0,0,0,0}, sqrow[4] = {0,0,0,0};
    #pragma unroll 1
    for (int i = 0; i < 4; i++){
      f32x4 a0={0,0,0,0},a1={0,0,0,0},a2={0,0,0,0},a3={0,0,0,0},a4={0,0,0,0},a5={0,0,0,0};
      #pragma unroll
      for (int a6 = 0; a6 < 6; a6++){
        #pragma unroll
        for (int cq = 0; cq < 4; cq++){
          const int pidx = i*24 + a6*4 + cq;      // chunk being consumed
          ISSUE4(pidx + 2, (a6*4 + cq + 2) % 3);  // wraps 96->0, 97->1 (slots match)
          VMW8;                                    // guarantees chunk pidx landed
          #pragma unroll
          for (int q = 0; q < 4; q++){
            half8 af = AFRAG((a6 < 3) ? xh_s : h_s, abase, cq*4 + q);
            half8 bf = RFR4((a6*4 + cq) % 3, q);
            if      (a6 == 0) a0 = MFMA(af, bf, a0);
            else if (a6 == 1) a1 = MFMA(af, bf, a1);
            else if (a6 == 2) a2 = MFMA(af, bf, a2);
            else if (a6 == 3) a3 = MFMA(af, bf, a3);
            else if (a6 == 4) a4 = MFMA(af, bf, a4);
            else              a5 = MFMA(af, bf, a5);
          }
        }
      }
      #pragma unroll
      for (int rr = 0; rr < 4; rr++){
        float rg = 1.f/(1.f + __expf(-(a0[rr] + a3[rr] + bcr[i])));
        float zg = 1.f/(1.f + __expf(-(a1[rr] + a4[rr] + bcz[i])));
        float aa = (a2[rr] + bin_[i]) + rg*(a5[rr] + bhn[i]);
        float ea = __expf(-2.f*fabsf(aa));
        float th = (1.f - ea)/(1.f + ea);
        float ng = (aa < 0.f) ? -th : th;
        float hv = (1.f - zg)*ng + zg*hreg[i][rr];
        hreg[i][rr] = hv;
        srow[rr] += hv; sqrow[rr] += hv*hv;
      }
    }
    #pragma unroll
    for (int d = 1; d < 16; d <<= 1){
      #pragma unroll
      for (int rr = 0; rr < 4; rr++){
        srow[rr]  += __shfl_xor(srow[rr],  d);
        sqrow[rr] += __shfl_xor(sqrow[rr], d);
      }
    }
    if (lo == 0){
      #pragma unroll
      for (int rr = 0; rr < 4; rr++){
        stats[((w*4 + hi)*4 + rr)*2 + 0] = srow[rr];
        stats[((w*4 + hi)*4 + rr)*2 + 1] = sqrow[rr];
      }
    }
    __syncthreads();   // full drain: wrap chunks 0,1 resident for next step
    if (w == 0 && lane < 16){
      float s = 0.f, q = 0.f;
      #pragma unroll
      for (int ww = 0; ww < 8; ww++){
        s += stats[((ww*4 + (lane>>2))*4 + (lane&3))*2 + 0];
        q += stats[((ww*4 + (lane>>2))*4 + (lane&3))*2 + 1];
      }
      float mu = s*(1.f/512.f);
      float var = q*(1.f/512.f) - mu*mu;
      murs[lane*2 + 0] = mu;
      murs[lane*2 + 1] = rsqrtf(var + 1e-5f);
    }
    __syncthreads();

    // ---- C: h -> h_s, layernorm(h) -> hn_s; hpre gather (nt); ends with drain ----
    float hp[4][4];
    #pragma unroll
    for (int rr = 0; rr < 4; rr++){
      int row = hi*4 + rr;
      float mu = murs[row*2 + 0], rs = murs[row*2 + 1];
      #pragma unroll
      for (int i = 0; i < 4; i++){
        int jc = w*64 + i*16 + lo;
        float hv = hreg[i][rr];
        WSTORE(h_s,  row, jc, hv);
        WSTORE(hn_s, row, jc, (hv - mu)*rs*lngv[i] + lnbv[i]);
        hp[i][rr] = (float)__builtin_nontemporal_load(
            &hpre[(((long)(r0 + row)*128 + t)*512) + jc]);
      }
    }
    __syncthreads();

    // ---- D (REGISTER PATH): hidden = relu(hn @ W_o1top + hpre + b_o1) ----
    // tiles ts = 384 + i*16 + ks; same bytes as r11's DMA path -> bit-identical
    #pragma unroll 1
    for (int i = 0; i < 4; i++){
      half8 bd[16];
      #pragma unroll
      for (int ks = 0; ks < 16; ks++)
        bd[ks] = *(const half8*)(pkw_w + (((long)(384 + i*16 + ks)) << 10) + (lane << 4));
      f32x4 dacc = {0,0,0,0};
      #pragma unroll
      for (int ks = 0; ks < 16; ks++)
        dacc = MFMA(AFRAG(hn_s, abase, ks), bd[ks], dacc);
      #pragma unroll
      for (int rr = 0; rr < 4; rr++){
        int row = hi*4 + rr;
        WSTORE(xh_s, row, w*64 + i*16 + lo, fmaxf(dacc[rr] + bo1v[i] + hp[i][rr], 0.f));
      }
    }
    __syncthreads();

    // ---- E (REGISTER PATH): logits = hidden @ W_o2 + b_o2 (w<4) ----
    if (w < 4){
      half8 be[16];
      #pragma unroll
      for (int ks = 0; ks < 16; ks++)
        be[ks] = *(const half8*)(pkw_w + (((long)(448 + ks)) << 10) + (lane << 4));
      f32x4 eacc = {0,0,0,0};
      #pragma unroll
      for (int ks = 0; ks < 16; ks++)
        eacc = MFMA(AFRAG(xh_s, abase, ks), be[ks], eacc);
      #pragma unroll
      for (int rr = 0; rr < 4; rr++){
        int row = hi*4 + rr;
        lg_s[row*64 + w*16 + lo] = eacc[rr] + bo2v;
      }
    }
    __syncthreads();

    // ---- F: out store (nt) + argmax (first-max tie), 2 rows/wave ----
    #pragma unroll
    for (int sub = 0; sub < 2; sub++){
      int r2 = w*2 + sub;
      float v = lg_s[r2*64 + lane];
      __builtin_nontemporal_store(v, &out[(((long)(r0 + r2))*128 + t)*64 + lane]);
      int idx = lane;
      #pragma unroll
      for (int d = 1; d < 64; d <<= 1){
        float ov = __shfl_xor(v, d);
        int oi = __shfl_xor(idx, d);
        if (ov > v || (ov == v && oi < idx)){ v = ov; idx = oi; }
      }
      if (lane == 0) pb[r2] = idx;
    }
    __syncthreads();
  }
}

extern "C" void kernel_launch(void* const* d_in, const int* in_sizes, int n_in,
                              void* d_out, int out_size, void* d_ws, size_t ws_size,
                              hipStream_t stream)
{
  const float* ctx    = (const float*)d_in[0];
  const int*   bh     = (const int*)d_in[1];
  const float* E      = (const float*)d_in[2];
  const float* W_in   = (const float*)d_in[3];
  const float* b_in   = (const float*)d_in[4];
  const float* W_init = (const float*)d_in[5];
  const float* b_init = (const float*)d_in[6];
  const float* W_ih   = (const float*)d_in[7];
  const float* W_hh   = (const float*)d_in[8];
  const float* b_ih   = (const float*)d_in[9];
  const float* b_hh   = (const float*)d_in[10];
  const float* ln_g   = (const float*)d_in[11];
  const float* ln_b   = (const float*)d_in[12];
  const float* W_o1   = (const float*)d_in[13];
  const float* b_o1   = (const float*)d_in[14];
  const float* W_o2   = (const float*)d_in[15];
  const float* b_o2   = (const float*)d_in[16];
  float* out = (float*)d_out;

  _Float16* pkw  = (_Float16*)d_ws;
  float*    Etab = (float*)((char*)d_ws + OFF_ETAB);
  float*    h0w  = (float*)((char*)d_ws + OFF_H0);
  _Float16* xpre = (_Float16*)((char*)d_ws + OFF_XPRE);
  _Float16* hpre = (_Float16*)((char*)d_ws + OFF_HPRE);

  (void)hipFuncSetAttribute((const void*)prep_k,
      hipFuncAttributeMaxDynamicSharedMemorySize, 65536);
  (void)hipFuncSetAttribute((const void*)main8_k,
      hipFuncAttributeMaxDynamicSharedMemorySize, 152768);

  hipLaunchKernelGGL(packw_k, dim3(468, 8), dim3(64), 0, stream, W_ih, W_hh, W_o1, W_o2, pkw);
  hipLaunchKernelGGL(etab_k, dim3(64), dim3(256), 0, stream, E, W_in, b_in, Etab);
  hipLaunchKernelGGL(h0_k, dim3(64), dim3(512), 0, stream, ctx, bh, E, W_init, b_init, h0w);
  hipLaunchKernelGGL(prep_k, dim3(1024), dim3(512), 65536, stream, ctx, W_in, W_o1, xpre, hpre);
  hipLaunchKernelGGL(main8_k, dim3(64), dim3(512), 152768, stream,
                     pkw, Etab, h0w, xpre, hpre, bh,
                     b_ih, b_hh, ln_g, ln_b, b_o1, b_o2, out);
}